// Round 8
// baseline (197.785 us; speedup 1.0000x reference)
//
#include <hip/hip_runtime.h>
#include <stdint.h>

#define BB 64
#define SS 512
#define DPP 12   // padded head dim (48B rows -> float4 aligned)
#define EPSF 1e-5f

typedef float v2f __attribute__((ext_vector_type(2)));

// ---------------- K1: LN1 + QKV projection ----------------
// grid 512 x 256. Block = 64 rows; wave = j-part (32 cols), lane = row.
__global__ __launch_bounds__(256) void k_ln_qkv(
    const float* __restrict__ x, const float* __restrict__ g, const float* __restrict__ be,
    const float* __restrict__ Wq, const float* __restrict__ bq,
    const float* __restrict__ Wk, const float* __restrict__ bk,
    const float* __restrict__ Wv, const float* __restrict__ bv,
    float* __restrict__ qo, float* __restrict__ ko, float* __restrict__ vo)
{
    __shared__ float sWT[40][128];   // [i][j], j=0..119 valid (q|k|v), 120..127 zero
    __shared__ float sBias[128];
    __shared__ float sG[40], sBt[40];
    __shared__ float sX[64][41];
    __shared__ float sOut[64][129];

    const int tid = threadIdx.x;
    for (int idx = tid; idx < 5120; idx += 256) {
        int i = idx >> 7, j = idx & 127;
        float val = 0.f;
        if (j < 40)       val = Wq[i * 40 + j];
        else if (j < 80)  val = Wk[i * 40 + (j - 40)];
        else if (j < 120) val = Wv[i * 40 + (j - 80)];
        sWT[i][j] = val;
    }
    if (tid < 128) {
        int j = tid;
        float val = 0.f;
        if (j < 40)       val = bq[j];
        else if (j < 80)  val = bk[j - 40];
        else if (j < 120) val = bv[j - 80];
        sBias[j] = val;
    }
    if (tid < 40) { sG[tid] = g[tid]; sBt[tid] = be[tid]; }

    const float4* xblk = (const float4*)(x + (size_t)blockIdx.x * 64 * 40);
    for (int idx = tid; idx < 640; idx += 256) {
        float4 u = xblk[idx];
        int fl = idx * 4;
        int r = fl / 40, c = fl - r * 40;
        sX[r][c] = u.x; sX[r][c + 1] = u.y; sX[r][c + 2] = u.z; sX[r][c + 3] = u.w;
    }
    __syncthreads();

    const int lane = tid & 63;
    const int part = tid >> 6;
    const int j0 = part * 32;

    // fused LN stats: one LDS pass
    float s1 = 0.f, s2 = 0.f;
#pragma unroll 8
    for (int i = 0; i < 40; i++) { float v = sX[lane][i]; s1 += v; s2 += v * v; }
    const float mu = s1 * 0.025f;
    const float rs = rsqrtf(s2 * 0.025f - mu * mu + EPSF);

    float acc[32];
#pragma unroll
    for (int jj = 0; jj < 32; jj++) acc[jj] = sBias[j0 + jj];
#pragma unroll 4
    for (int i = 0; i < 40; i++) {
        const float hi = (sX[lane][i] - mu) * rs * sG[i] + sBt[i];
        const float4* wrow = (const float4*)&sWT[i][j0];
#pragma unroll
        for (int c = 0; c < 8; c++) {
            float4 wv = wrow[c];
            acc[c * 4 + 0] += hi * wv.x;
            acc[c * 4 + 1] += hi * wv.y;
            acc[c * 4 + 2] += hi * wv.z;
            acc[c * 4 + 3] += hi * wv.w;
        }
    }
#pragma unroll
    for (int jj = 0; jj < 32; jj++) sOut[lane][j0 + jj] = acc[jj];
    __syncthreads();

    const int row0 = blockIdx.x * 64;
    const int b4 = (row0 >> 9) * 4, s0 = row0 & 511;
    for (int fi = tid; fi < 2304; fi += 256) {
        int region = fi / 192;
        int kk = fi - region * 192;
        int w = region >> 2, hh = region & 3;
        int r = kk / 3, gg = kk - r * 3;
        int bj = w * 40 + hh * 10 + gg * 4;
        float4 val;
        val.x = sOut[r][bj];
        val.y = sOut[r][bj + 1];
        val.z = (gg == 2) ? 0.f : sOut[r][bj + 2];
        val.w = (gg == 2) ? 0.f : sOut[r][bj + 3];
        float* op = (w == 0) ? qo : (w == 1) ? ko : vo;
        *(float4*)(op + ((size_t)((b4 + hh) * 512 + s0 + r)) * DPP + gg * 4) = val;
    }
}

// ---------------- K2: attention v8 ----------------
// grid 512 = bh x q-half (256 q). block 256 = 4 waves = k-quarters (128 keys).
// QPT=4. K/V are wave-broadcast reads -> read DIRECTLY from global (L1/L2
// broadcast), register double-buffer prefetch one key-pair ahead. LDS only
// holds a 12KB atomic merge buffer. No max-tracking (scores bounded).
__global__ __launch_bounds__(256, 2) void k_attn(
    const float* __restrict__ qg, const float* __restrict__ kg,
    const float* __restrict__ vg, float* __restrict__ ctx)
{
    __shared__ float sAcc[256][12];      // [q][a0..a9, l, pad]

    const int tid = threadIdx.x;
    const int bh = blockIdx.x >> 1;
    const int qh = blockIdx.x & 1;
    const int lane = tid & 63;
    const int wave = tid >> 6;           // k-quarter

    {   // zero merge buffer
        float4 z = {0.f, 0.f, 0.f, 0.f};
        float4* az = (float4*)sAcc;
        az[tid] = z; az[tid + 256] = z; az[tid + 512] = z;
    }
    __syncthreads();

    const float cscale = 1.4426950408889634f / 3.1622776601683795f;  // log2e/sqrt(10)
    v2f q[4][5];
#pragma unroll
    for (int jj = 0; jj < 4; jj++) {
        const float2* qp = (const float2*)(qg + ((size_t)bh * 512 + qh * 256 + jj * 64 + lane) * DPP);
#pragma unroll
        for (int c = 0; c < 5; c++) {
            float2 u = qp[c];
            v2f t; t.x = u.x * cscale; t.y = u.y * cscale;
            q[jj][c] = t;
        }
    }

    float l[4] = {0.f, 0.f, 0.f, 0.f};
    v2f a[4][5];
#pragma unroll
    for (int jj = 0; jj < 4; jj++)
#pragma unroll
        for (int d = 0; d < 5; d++) a[jj][d] = (v2f)(0.f);

    const float4* kp = (const float4*)(kg + (size_t)bh * 512 * DPP) + (size_t)wave * 128 * 3;
    const float4* vp = (const float4*)(vg + (size_t)bh * 512 * DPP) + (size_t)wave * 128 * 3;

    // current key-pair buffers
    float4 ka0 = kp[0], ka1 = kp[1], ka2 = kp[2];
    float4 kb0 = kp[3], kb1 = kp[4], kb2 = kp[5];
    float4 va0 = vp[0], va1 = vp[1], va2 = vp[2];
    float4 vb0 = vp[3], vb1 = vp[4], vb2 = vp[5];

    for (int kt = 0; kt < 128; kt += 2) {
        // prefetch next pair (kt+2); overread at kt=126 lands in the
        // following ws array (k->v->ctx contiguous) and is never used.
        const int nb = (kt + 2) * 3;
        float4 nka0 = kp[nb + 0], nka1 = kp[nb + 1], nka2 = kp[nb + 2];
        float4 nkb0 = kp[nb + 3], nkb1 = kp[nb + 4], nkb2 = kp[nb + 5];
        float4 nva0 = vp[nb + 0], nva1 = vp[nb + 1], nva2 = vp[nb + 2];
        float4 nvb0 = vp[nb + 3], nvb1 = vp[nb + 4], nvb2 = vp[nb + 5];

        v2f ka[5], kb[5], va[5], vb[5];
        ka[0] = v2f{ka0.x, ka0.y}; ka[1] = v2f{ka0.z, ka0.w};
        ka[2] = v2f{ka1.x, ka1.y}; ka[3] = v2f{ka1.z, ka1.w};
        ka[4] = v2f{ka2.x, ka2.y};
        kb[0] = v2f{kb0.x, kb0.y}; kb[1] = v2f{kb0.z, kb0.w};
        kb[2] = v2f{kb1.x, kb1.y}; kb[3] = v2f{kb1.z, kb1.w};
        kb[4] = v2f{kb2.x, kb2.y};
        va[0] = v2f{va0.x, va0.y}; va[1] = v2f{va0.z, va0.w};
        va[2] = v2f{va1.x, va1.y}; va[3] = v2f{va1.z, va1.w};
        va[4] = v2f{va2.x, va2.y};
        vb[0] = v2f{vb0.x, vb0.y}; vb[1] = v2f{vb0.z, vb0.w};
        vb[2] = v2f{vb1.x, vb1.y}; vb[3] = v2f{vb1.z, vb1.w};
        vb[4] = v2f{vb2.x, vb2.y};

#pragma unroll
        for (int jj = 0; jj < 4; jj++) {
            v2f da = q[jj][0] * ka[0];
            v2f db = q[jj][0] * kb[0];
#pragma unroll
            for (int c = 1; c < 5; c++) {
                da += q[jj][c] * ka[c];
                db += q[jj][c] * kb[c];
            }
            const float pa = __builtin_amdgcn_exp2f(da.x + da.y);
            const float pb = __builtin_amdgcn_exp2f(db.x + db.y);
            l[jj] += pa + pb;
            const v2f pa2 = {pa, pa};
            const v2f pb2 = {pb, pb};
#pragma unroll
            for (int d = 0; d < 5; d++)
                a[jj][d] += pa2 * va[d] + pb2 * vb[d];
        }

        ka0 = nka0; ka1 = nka1; ka2 = nka2;
        kb0 = nkb0; kb1 = nkb1; kb2 = nkb2;
        va0 = nva0; va1 = nva1; va2 = nva2;
        vb0 = nvb0; vb1 = nvb1; vb2 = nvb2;
    }

    // atomic merge of the 4 k-quarter partials
#pragma unroll
    for (int jj = 0; jj < 4; jj++) {
        float* base = &sAcc[jj * 64 + lane][0];
        atomicAdd(base + 0, a[jj][0].x); atomicAdd(base + 1, a[jj][0].y);
        atomicAdd(base + 2, a[jj][1].x); atomicAdd(base + 3, a[jj][1].y);
        atomicAdd(base + 4, a[jj][2].x); atomicAdd(base + 5, a[jj][2].y);
        atomicAdd(base + 6, a[jj][3].x); atomicAdd(base + 7, a[jj][3].y);
        atomicAdd(base + 8, a[jj][4].x); atomicAdd(base + 9, a[jj][4].y);
        atomicAdd(base + 10, l[jj]);
    }
    __syncthreads();

    // normalize + write: one query per thread
    {
        const float4* pr = (const float4*)&sAcc[tid][0];
        float4 u0 = pr[0], u1 = pr[1], u2 = pr[2];
        const float inv = 1.f / u2.z;
        float* op = ctx + ((size_t)bh * 512 + qh * 256 + tid) * 10;
        float2 w;
        w.x = u0.x * inv; w.y = u0.y * inv; *(float2*)(op + 0) = w;
        w.x = u0.z * inv; w.y = u0.w * inv; *(float2*)(op + 2) = w;
        w.x = u1.x * inv; w.y = u1.y * inv; *(float2*)(op + 4) = w;
        w.x = u1.z * inv; w.y = u1.w * inv; *(float2*)(op + 6) = w;
        w.x = u2.x * inv; w.y = u2.y * inv; *(float2*)(op + 8) = w;
    }
}

// ---------------- K3: Wo + residual + LN2 + FFN + residual ----------------
// grid 512 x 256. Block = 64 rows; wave = col-slice, lane = row.
__global__ __launch_bounds__(256) void k_out_ffn(
    const float* __restrict__ ctx, const float* __restrict__ x,
    const float* __restrict__ Wo, const float* __restrict__ bo,
    const float* __restrict__ g2, const float* __restrict__ bt2,
    const float* __restrict__ W1, const float* __restrict__ b1,
    const float* __restrict__ W2, const float* __restrict__ b2,
    float* __restrict__ out)
{
    __shared__ float sWo[40][48];
    __shared__ float sW1[40][32];
    __shared__ float sW2[20][48];
    __shared__ float sBo[40], sG2[40], sBt2[40], sB1[20], sB2[40];
    __shared__ float sCtx[64][41];
    __shared__ float sH[64][41];
    __shared__ float sIt[64][21];
    __shared__ float sSum[64][4], sSum2[64][4];

    const int tid = threadIdx.x;
    for (int idx = tid; idx < 1600; idx += 256) {
        int i = idx / 40, j = idx % 40;
        sWo[i][(j / 10) * 12 + (j % 10)] = Wo[idx];
    }
    for (int idx = tid; idx < 800; idx += 256) {
        {
            int i = idx / 20, j = idx % 20;
            sW1[i][(j / 5) * 8 + (j % 5)] = W1[idx];
        }
        {
            int i = idx / 40, j = idx % 40;
            sW2[i][(j / 10) * 12 + (j % 10)] = W2[idx];
        }
    }
    if (tid < 40) { sBo[tid] = bo[tid]; sG2[tid] = g2[tid]; sBt2[tid] = bt2[tid]; sB2[tid] = b2[tid]; }
    if (tid < 20) sB1[tid] = b1[tid];

    const int row0 = blockIdx.x * 64;
    const int b = row0 >> 9, s0 = row0 & 511;

    for (int idx = tid; idx < 640; idx += 256) {
        const int hh = idx / 160, f = idx - hh * 160;
        float4 u = *(const float4*)(ctx + ((size_t)((b * 4 + hh) * 512 + s0)) * 10 + f * 4);
        const int fo = f * 4;
        float e[4] = {u.x, u.y, u.z, u.w};
#pragma unroll
        for (int t = 0; t < 4; t++) {
            const int fe = fo + t;
            const int r = fe / 10, c = fe - r * 10;
            sCtx[r][hh * 10 + c] = e[t];
        }
    }
    const float4* xblk = (const float4*)(x + (size_t)blockIdx.x * 64 * 40);
    for (int idx = tid; idx < 640; idx += 256) {
        float4 w = xblk[idx];
        int fl = idx * 4;
        int r = fl / 40, c = fl - r * 40;
        sH[r][c] = w.x; sH[r][c + 1] = w.y; sH[r][c + 2] = w.z; sH[r][c + 3] = w.w;
    }
    __syncthreads();

    const int lane = tid & 63;
    const int wv = tid >> 6;
    const int j0 = wv * 10;

    float acc[10];
#pragma unroll
    for (int j = 0; j < 10; j++) acc[j] = sBo[j0 + j] + sH[lane][j0 + j];
#pragma unroll 8
    for (int i = 0; i < 40; i++) {
        const float ci = sCtx[lane][i];
        const float4* wrow = (const float4*)&sWo[i][wv * 12];
        float4 w0 = wrow[0], w1 = wrow[1], w2 = wrow[2];
        acc[0] += ci * w0.x; acc[1] += ci * w0.y; acc[2] += ci * w0.z; acc[3] += ci * w0.w;
        acc[4] += ci * w1.x; acc[5] += ci * w1.y; acc[6] += ci * w1.z; acc[7] += ci * w1.w;
        acc[8] += ci * w2.x; acc[9] += ci * w2.y;
    }
    {
        float s1 = 0.f, s2 = 0.f;
#pragma unroll
        for (int j = 0; j < 10; j++) { s1 += acc[j]; s2 += acc[j] * acc[j]; }
        sSum[lane][wv] = s1; sSum2[lane][wv] = s2;
    }
    __syncthreads();
    const float mu = (sSum[lane][0] + sSum[lane][1] + sSum[lane][2] + sSum[lane][3]) * 0.025f;
    const float ex2 = (sSum2[lane][0] + sSum2[lane][1] + sSum2[lane][2] + sSum2[lane][3]) * 0.025f;
    const float rs = rsqrtf(ex2 - mu * mu + EPSF);
#pragma unroll
    for (int j = 0; j < 10; j++)
        sH[lane][j0 + j] = (acc[j] - mu) * rs * sG2[j0 + j] + sBt2[j0 + j];
    __syncthreads();

    const int f0 = wv * 5;
    float it[5];
#pragma unroll
    for (int j = 0; j < 5; j++) it[j] = sB1[f0 + j];
#pragma unroll 8
    for (int i = 0; i < 40; i++) {
        const float hi = sH[lane][i];
        const float4* wrow = (const float4*)&sW1[i][wv * 8];
        float4 w0 = wrow[0], w1 = wrow[1];
        it[0] += hi * w0.x; it[1] += hi * w0.y; it[2] += hi * w0.z; it[3] += hi * w0.w;
        it[4] += hi * w1.x;
    }
#pragma unroll
    for (int j = 0; j < 5; j++) {
        float t = it[j];
        sIt[lane][f0 + j] = 0.5f * t * (1.0f + erff(t * 0.70710678118654752f));
    }
    __syncthreads();

    float o[10];
#pragma unroll
    for (int j = 0; j < 10; j++) o[j] = acc[j] + sB2[j0 + j];
#pragma unroll 4
    for (int i = 0; i < 20; i++) {
        const float ii = sIt[lane][i];
        const float4* wrow = (const float4*)&sW2[i][wv * 12];
        float4 w0 = wrow[0], w1 = wrow[1], w2 = wrow[2];
        o[0] += ii * w0.x; o[1] += ii * w0.y; o[2] += ii * w0.z; o[3] += ii * w0.w;
        o[4] += ii * w1.x; o[5] += ii * w1.y; o[6] += ii * w1.z; o[7] += ii * w1.w;
        o[8] += ii * w2.x; o[9] += ii * w2.y;
    }
#pragma unroll
    for (int j = 0; j < 10; j++) sCtx[lane][j0 + j] = o[j];
    __syncthreads();

    float4* oblk = (float4*)(out + (size_t)blockIdx.x * 64 * 40);
    for (int idx = tid; idx < 640; idx += 256) {
        int fl = idx * 4;
        int r = fl / 40, c = fl - r * 40;
        float4 u;
        u.x = sCtx[r][c]; u.y = sCtx[r][c + 1]; u.z = sCtx[r][c + 2]; u.w = sCtx[r][c + 3];
        oblk[idx] = u;
    }
}

extern "C" void kernel_launch(void* const* d_in, const int* in_sizes, int n_in,
                              void* d_out, int out_size, void* d_ws, size_t ws_size,
                              hipStream_t stream)
{
    const float* x   = (const float*)d_in[0];
    const float* g1  = (const float*)d_in[1];
    const float* be1 = (const float*)d_in[2];
    const float* Wq  = (const float*)d_in[3];
    const float* bq  = (const float*)d_in[4];
    const float* Wk  = (const float*)d_in[5];
    const float* bk  = (const float*)d_in[6];
    const float* Wv  = (const float*)d_in[7];
    const float* bv  = (const float*)d_in[8];
    const float* Wo  = (const float*)d_in[9];
    const float* bo  = (const float*)d_in[10];
    const float* g2  = (const float*)d_in[11];
    const float* bt2 = (const float*)d_in[12];
    const float* W1  = (const float*)d_in[13];
    const float* b1  = (const float*)d_in[14];
    const float* W2  = (const float*)d_in[15];
    const float* b2  = (const float*)d_in[16];

    float* ws = (float*)d_ws;
    const size_t QKV = (size_t)BB * 4 * SS * DPP;  // 1,572,864 floats
    float* q   = ws;
    float* k   = ws + QKV;
    float* v   = ws + 2 * QKV;
    float* ctx = ws + 3 * QKV;  // [B,H,S,10] = 1,310,720 floats

    k_ln_qkv<<<512, 256, 0, stream>>>(x, g1, be1, Wq, bq, Wk, bk, Wv, bv, q, k, v);
    k_attn<<<512, 256, 0, stream>>>(q, k, v, ctx);
    k_out_ffn<<<512, 256, 0, stream>>>(ctx, x, Wo, bo, g2, bt2, W1, b1, W2, b2,
                                       (float*)d_out);
}